// Round 3
// baseline (598.228 us; speedup 1.0000x reference)
//
#include <hip/hip_runtime.h>
#include <hip/hip_fp16.h>

#define F_IN 128
#define HID  64
#define NCLS 16
#define NPB  128      // nodes per bucket (pow2); bucket = col >> 7
#define CAP  4096     // edge slots reserved per bucket (2x mean 2046)
#define CHUNK 4096    // edges per binning task (= 16 * 256 exactly)

typedef _Float16 half_t;
typedef __attribute__((ext_vector_type(8))) _Float16 half8;
typedef __attribute__((ext_vector_type(4))) float float4v;

// ---------------- device-scope grid barrier (sense-reversal, agent scope) ----------------
// Requires all blocks co-resident: guaranteed via occupancy-clamped grid at launch.

__device__ inline void gridbar(int* cnt, int* gen) {
    __syncthreads();
    if (threadIdx.x == 0) {
        __threadfence();   // release my block's global writes device-wide
        int g = __hip_atomic_load(gen, __ATOMIC_RELAXED, __HIP_MEMORY_SCOPE_AGENT);
        int n = (int)gridDim.x;
        if (__hip_atomic_fetch_add(cnt, 1, __ATOMIC_ACQ_REL, __HIP_MEMORY_SCOPE_AGENT) == n - 1) {
            __hip_atomic_store(cnt, 0, __ATOMIC_RELAXED, __HIP_MEMORY_SCOPE_AGENT);
            __hip_atomic_fetch_add(gen, 1, __ATOMIC_ACQ_REL, __HIP_MEMORY_SCOPE_AGENT);
        } else {
            while (__hip_atomic_load(gen, __ATOMIC_ACQUIRE, __HIP_MEMORY_SCOPE_AGENT) == g)
                __builtin_amdgcn_s_sleep(8);
        }
        __threadfence();   // acquire: subsequent loads see other blocks' writes
    }
    __syncthreads();
}

// ---------------- ONE persistent kernel, 4 phases, 3 grid barriers ----------------

__global__ __launch_bounds__(256, 4) void fused_gcn(
    const int* __restrict__ row, const int* __restrict__ col,
    const float* __restrict__ x, const float* __restrict__ W1,
    const float* __restrict__ b1, const float* __restrict__ W2,
    const float* __restrict__ b2, float* __restrict__ out,
    int* __restrict__ cursor, int* __restrict__ ebuf,
    half_t* __restrict__ W1t, int2* __restrict__ rsc,
    int* __restrict__ csr_row, __half* __restrict__ hs1,
    __half* __restrict__ h2s, int* __restrict__ bar,
    int N, int E, int NB)
{
    __shared__ char smem[12544];                 // union across phases (12.4 KB)
    int*   smem_i = (int*)smem;
    float* smem_f = (float*)smem;
    int t = threadIdx.x;

    // ================= Phase 1: bin edges into capped bucket regions + W1 prep =================
    {
        int* histB = smem_i;                     // [1024]
        int* baseB = smem_i + 1024;              // [1024]
        int* offB  = smem_i + 2048;              // [1024]
        int nch = (E + CHUNK - 1) / CHUNK;
        for (int ch = blockIdx.x; ch <= nch; ch += gridDim.x) {
            if (ch == nch) {                     // W1 transpose task
                for (int i = t; i < F_IN * HID; i += 256) {
                    int k = i >> 6, n = i & 63;
                    W1t[n * F_IN + k] = (half_t)W1[i];
                }
                continue;
            }
            for (int i = t; i < NB; i += 256) histB[i] = 0;
            int e0 = ch * CHUNK + t * 16;
            int4 c4[4], r4[4];
            int nvv[4];
            #pragma unroll
            for (int j = 0; j < 4; ++j) {
                int ej = e0 + j * 4;
                int nv = min(max(E - ej, 0), 4);
                nvv[j] = nv;
                c4[j] = make_int4(0, 0, 0, 0); r4[j] = make_int4(0, 0, 0, 0);
                if (nv == 4) {                   // 16B-aligned fast path
                    c4[j] = *(const int4*)&col[ej];
                    r4[j] = *(const int4*)&row[ej];
                } else {
                    if (nv > 0) { c4[j].x = col[ej + 0]; r4[j].x = row[ej + 0]; }
                    if (nv > 1) { c4[j].y = col[ej + 1]; r4[j].y = row[ej + 1]; }
                    if (nv > 2) { c4[j].z = col[ej + 2]; r4[j].z = row[ej + 2]; }
                }
            }
            __syncthreads();                     // hist zeroed
            #pragma unroll
            for (int j = 0; j < 4; ++j) {
                if (nvv[j] > 0) atomicAdd(&histB[c4[j].x >> 7], 1);
                if (nvv[j] > 1) atomicAdd(&histB[c4[j].y >> 7], 1);
                if (nvv[j] > 2) atomicAdd(&histB[c4[j].z >> 7], 1);
                if (nvv[j] > 3) atomicAdd(&histB[c4[j].w >> 7], 1);
            }
            __syncthreads();
            for (int i = t; i < NB; i += 256) {
                int h = histB[i];
                baseB[i] = h ? (i * CAP + atomicAdd(&cursor[i], h)) : 0;
                offB[i] = 0;
            }
            __syncthreads();
            #pragma unroll
            for (int j = 0; j < 4; ++j) {
                if (nvv[j] > 0) { int b = c4[j].x >> 7; int p = baseB[b] + atomicAdd(&offB[b], 1);
                                  if (p < (b + 1) * CAP) ebuf[p] = (r4[j].x << 7) | (c4[j].x & (NPB - 1)); }
                if (nvv[j] > 1) { int b = c4[j].y >> 7; int p = baseB[b] + atomicAdd(&offB[b], 1);
                                  if (p < (b + 1) * CAP) ebuf[p] = (r4[j].y << 7) | (c4[j].y & (NPB - 1)); }
                if (nvv[j] > 2) { int b = c4[j].z >> 7; int p = baseB[b] + atomicAdd(&offB[b], 1);
                                  if (p < (b + 1) * CAP) ebuf[p] = (r4[j].z << 7) | (c4[j].z & (NPB - 1)); }
                if (nvv[j] > 3) { int b = c4[j].w >> 7; int p = baseB[b] + atomicAdd(&offB[b], 1);
                                  if (p < (b + 1) * CAP) ebuf[p] = (r4[j].w << 7) | (c4[j].w & (NPB - 1)); }
            }
            __syncthreads();                     // LDS reuse guard before next chunk
        }
    }
    gridbar(bar, bar + 1);

    // ================= Phase 2: two task families -- GEMM (dv + 128x64 MFMA) and CSR build =================
    {
        int*   hist = smem_i;                    // [128]
        float* dv   = smem_f + 128;              // [128]
        int*   cur  = smem_i + 256;              // [128]
        int*   wtot = smem_i + 384;
        int ntask = 2 * NB;
        for (int task = blockIdx.x; task < ntask; task += gridDim.x) {
            __syncthreads();                     // LDS reuse guard between tasks
            if (task < NB) {
                // ---- GEMM family ----
                int b = task;
                int node0 = b << 7;
                int ebase = b * CAP;
                int p[8];
                #pragma unroll
                for (int k = 0; k < 8; ++k) p[k] = ebuf[ebase + t + 256 * k];
                int cnt = min(cursor[b], CAP);
                if (t < NPB) hist[t] = 0;
                __syncthreads();
                #pragma unroll
                for (int k = 0; k < 8; ++k)
                    if (t + 256 * k < cnt) atomicAdd(&hist[p[k] & (NPB - 1)], 1);
                if (cnt > 2048)
                    for (int e = 2048 + t; e < cnt; e += 256)
                        atomicAdd(&hist[ebuf[ebase + e] & (NPB - 1)], 1);
                __syncthreads();
                if (t < NPB) dv[t] = rsqrtf((float)hist[t] + 1.0f);   // +1 = self-loop
                __syncthreads();

                int wv = t >> 6, lane = t & 63;
                int l15 = lane & 15, quad = lane >> 4;
                int mbase = wv * 32;
                int r0 = min(node0 + mbase + l15, N - 1);
                int r1 = min(node0 + mbase + 16 + l15, N - 1);
                const float* x0 = x + (size_t)r0 * F_IN;
                const float* x1 = x + (size_t)r1 * F_IN;
                float4v acc[2][4];
                #pragma unroll
                for (int mt = 0; mt < 2; ++mt)
                    #pragma unroll
                    for (int j = 0; j < 4; ++j) acc[mt][j] = (float4v){0.f, 0.f, 0.f, 0.f};
                #pragma unroll
                for (int kb = 0; kb < 4; ++kb) {
                    int off = kb * 32 + quad * 8;
                    float4 fa = *(const float4*)&x0[off];
                    float4 fb = *(const float4*)&x0[off + 4];
                    float4 ga = *(const float4*)&x1[off];
                    float4 gb = *(const float4*)&x1[off + 4];
                    half8 a0 = {(half_t)fa.x, (half_t)fa.y, (half_t)fa.z, (half_t)fa.w,
                                (half_t)fb.x, (half_t)fb.y, (half_t)fb.z, (half_t)fb.w};
                    half8 a1 = {(half_t)ga.x, (half_t)ga.y, (half_t)ga.z, (half_t)ga.w,
                                (half_t)gb.x, (half_t)gb.y, (half_t)gb.z, (half_t)gb.w};
                    #pragma unroll
                    for (int j = 0; j < 4; ++j) {
                        half8 bv = *(const half8*)&W1t[(size_t)(j * 16 + l15) * F_IN + off];
                        acc[0][j] = __builtin_amdgcn_mfma_f32_16x16x32_f16(a0, bv, acc[0][j], 0, 0, 0);
                        acc[1][j] = __builtin_amdgcn_mfma_f32_16x16x32_f16(a1, bv, acc[1][j], 0, 0, 0);
                    }
                }
                // C/D: col(n) = l15, row(m) = quad*4 + r
                #pragma unroll
                for (int mt = 0; mt < 2; ++mt)
                    #pragma unroll
                    for (int j = 0; j < 4; ++j)
                        #pragma unroll
                        for (int r = 0; r < 4; ++r) {
                            int m = mbase + mt * 16 + quad * 4 + r;
                            int n = node0 + m;
                            if (n < N) hs1[(size_t)n * HID + j * 16 + l15] =
                                __float2half(acc[mt][j][r] * dv[m]);
                        }
            } else {
                // ---- CSR family ----
                int b = task - NB;
                int node0 = b << 7;
                int ebase = b * CAP;
                int p[8];
                #pragma unroll
                for (int k = 0; k < 8; ++k) p[k] = ebuf[ebase + t + 256 * k];
                int cnt = min(cursor[b], CAP);
                if (t < NPB) hist[t] = 0;
                __syncthreads();
                #pragma unroll
                for (int k = 0; k < 8; ++k)
                    if (t + 256 * k < cnt) atomicAdd(&hist[p[k] & (NPB - 1)], 1);
                if (cnt > 2048)
                    for (int e = 2048 + t; e < cnt; e += 256)
                        atomicAdd(&hist[ebuf[ebase + e] & (NPB - 1)], 1);
                __syncthreads();
                int h = 0, incl = 0;
                if (t < NPB) {                   // waves 0,1 fully active
                    h = hist[t];
                    incl = h;
                    #pragma unroll
                    for (int off = 1; off < 64; off <<= 1) {
                        int u = __shfl_up(incl, off, 64);
                        if ((t & 63) >= off) incl += u;
                    }
                    if (t == 63) *wtot = incl;
                }
                __syncthreads();
                if (t < NPB) {
                    if (t >= 64) incl += *wtot;
                    int start = ebase + incl - h;   // exclusive, absolute in region space
                    cur[t] = start;
                    int n = node0 + t;
                    if (n < N) rsc[n] = make_int2(start, h);
                }
                __syncthreads();
                #pragma unroll
                for (int k = 0; k < 8; ++k)
                    if (t + 256 * k < cnt) {
                        int pos = atomicAdd(&cur[p[k] & (NPB - 1)], 1);
                        csr_row[pos] = p[k] >> 7;
                    }
                if (cnt > 2048)
                    for (int e = 2048 + t; e < cnt; e += 256) {
                        int pp = ebuf[ebase + e];
                        int pos = atomicAdd(&cur[pp & (NPB - 1)], 1);
                        csr_row[pos] = pp >> 7;
                    }
            }
        }
    }
    gridbar(bar, bar + 1);

    // ================= Phase 3: layer-1 gather-aggregate + relu + @W2 =================
    {
        float* W2l = smem_f;                     // [1024], index k*16+j
        float* o1  = smem_f + 1024;              // [32][65] strided
        for (int i = t; i < HID * NCLS; i += 256) W2l[i] = W2[i];
        __syncthreads();
        int w = t >> 6, lane = t & 63;
        int g = lane >> 3, gl = lane & 7;
        int rowi = w * 8 + g;
        float* orow = o1 + rowi * 65;
        const half8* H = (const half8*)hs1;      // 8 half8 per row
        int nt3 = (N + 31) >> 5;
        for (int vb = blockIdx.x; vb < nt3; vb += gridDim.x) {
            int c = vb * 32 + rowi;
            bool active = (c < N);
            int cc = active ? c : 0;
            int2 rc = rsc[cc];
            int e0 = rc.x, e1 = rc.x + rc.y;
            float dc = rsqrtf((float)rc.y + 1.0f);
            half8 sv = H[(size_t)cc * 8 + gl];   // self-loop (hs1 pre-scaled by dinv[src])
            float sum[8];
            #pragma unroll
            for (int k = 0; k < 8; ++k) sum[k] = (float)sv[k];
            int i = e0;
            for (; i + 8 <= e1; i += 8) {        // full blocks: no predication
                int id[8];
                #pragma unroll
                for (int s = 0; s < 8; ++s) id[s] = csr_row[i + s];
                half8 a[8];
                #pragma unroll
                for (int s = 0; s < 8; ++s) a[s] = H[(size_t)id[s] * 8 + gl];
                half8 t0 = a[0] + a[1];          // packed-fp16 pairwise tree
                half8 t1 = a[2] + a[3];
                half8 t2 = a[4] + a[5];
                half8 t3 = a[6] + a[7];
                half8 v = (t0 + t1) + (t2 + t3);
                #pragma unroll
                for (int k = 0; k < 8; ++k) sum[k] += (float)v[k];
            }
            if (i < e1) {                        // tail (<8 edges), predicated
                int e1m1 = e1 - 1;
                int id[8];
                #pragma unroll
                for (int s = 0; s < 8; ++s) id[s] = csr_row[min(i + s, e1m1)];
                half8 a[8];
                #pragma unroll
                for (int s = 0; s < 8; ++s) a[s] = H[(size_t)id[s] * 8 + gl];
                #pragma unroll
                for (int s = 0; s < 8; ++s) {
                    float fm = (i + s < e1) ? 1.f : 0.f;
                    #pragma unroll
                    for (int k = 0; k < 8; ++k) sum[k] = fmaf(fm, (float)a[s][k], sum[k]);
                }
            }
            float4 bb0 = *(const float4*)&b1[gl * 8];
            float4 bb1 = *(const float4*)&b1[gl * 8 + 4];
            orow[gl * 8 + 0] = fmaxf(fmaf(dc, sum[0], bb0.x), 0.f);
            orow[gl * 8 + 1] = fmaxf(fmaf(dc, sum[1], bb0.y), 0.f);
            orow[gl * 8 + 2] = fmaxf(fmaf(dc, sum[2], bb0.z), 0.f);
            orow[gl * 8 + 3] = fmaxf(fmaf(dc, sum[3], bb0.w), 0.f);
            orow[gl * 8 + 4] = fmaxf(fmaf(dc, sum[4], bb1.x), 0.f);
            orow[gl * 8 + 5] = fmaxf(fmaf(dc, sum[5], bb1.y), 0.f);
            orow[gl * 8 + 6] = fmaxf(fmaf(dc, sum[6], bb1.z), 0.f);
            orow[gl * 8 + 7] = fmaxf(fmaf(dc, sum[7], bb1.w), 0.f);
            // same-wave LDS write->read: no barrier needed.
            int j0 = gl * 2, j1 = gl * 2 + 1;
            float s0 = 0.f, s1 = 0.f;
            #pragma unroll 8
            for (int k = 0; k < HID; ++k) {
                float ov = orow[k];
                s0 = fmaf(ov, W2l[k * NCLS + j0], s0);
                s1 = fmaf(ov, W2l[k * NCLS + j1], s1);
            }
            if (active) {
                __half2 hv;
                hv.x = __float2half(dc * s0);
                hv.y = __float2half(dc * s1);
                ((__half2*)h2s)[(size_t)c * 8 + gl] = hv;
            }
        }
    }
    gridbar(bar, bar + 1);

    // ================= Phase 4: layer-2 gather-aggregate + log_softmax =================
    {
        int w = t >> 6, lane = t & 63;
        int nw = lane >> 1, hl = lane & 1;
        const half8* H = (const half8*)h2s;      // 2 half8 per row (32B)
        float4 bb0 = *(const float4*)&b2[hl * 8];
        float4 bb1 = *(const float4*)&b2[hl * 8 + 4];
        int nt4 = (N + 127) >> 7;
        for (int vb = blockIdx.x; vb < nt4; vb += gridDim.x) {
            int c = vb * 128 + w * 32 + nw;
            bool active = (c < N);
            int cc = active ? c : 0;
            int2 rc = rsc[cc];
            int e0 = rc.x, e1 = rc.x + rc.y;
            float dcv = rsqrtf((float)rc.y + 1.0f);
            half8 sv = H[(size_t)cc * 2 + hl];   // self-loop
            float sum[8];
            #pragma unroll
            for (int k = 0; k < 8; ++k) sum[k] = (float)sv[k];
            int i = e0;
            for (; i + 8 <= e1; i += 8) {
                int id[8];
                #pragma unroll
                for (int s = 0; s < 8; ++s) id[s] = csr_row[i + s];
                half8 a[8];
                #pragma unroll
                for (int s = 0; s < 8; ++s) a[s] = H[(size_t)id[s] * 2 + hl];
                half8 t0 = a[0] + a[1];
                half8 t1 = a[2] + a[3];
                half8 t2 = a[4] + a[5];
                half8 t3 = a[6] + a[7];
                half8 v = (t0 + t1) + (t2 + t3);
                #pragma unroll
                for (int k = 0; k < 8; ++k) sum[k] += (float)v[k];
            }
            if (i < e1) {
                int e1m1 = e1 - 1;
                int id[8];
                #pragma unroll
                for (int s = 0; s < 8; ++s) id[s] = csr_row[min(i + s, e1m1)];
                half8 a[8];
                #pragma unroll
                for (int s = 0; s < 8; ++s) a[s] = H[(size_t)id[s] * 2 + hl];
                #pragma unroll
                for (int s = 0; s < 8; ++s) {
                    float fm = (i + s < e1) ? 1.f : 0.f;
                    #pragma unroll
                    for (int k = 0; k < 8; ++k) sum[k] = fmaf(fm, (float)a[s][k], sum[k]);
                }
            }
            float v0 = fmaf(dcv, sum[0], bb0.x);
            float v1 = fmaf(dcv, sum[1], bb0.y);
            float v2 = fmaf(dcv, sum[2], bb0.z);
            float v3 = fmaf(dcv, sum[3], bb0.w);
            float v4 = fmaf(dcv, sum[4], bb1.x);
            float v5 = fmaf(dcv, sum[5], bb1.y);
            float v6 = fmaf(dcv, sum[6], bb1.z);
            float v7 = fmaf(dcv, sum[7], bb1.w);
            float mx = fmaxf(fmaxf(fmaxf(v0, v1), fmaxf(v2, v3)),
                             fmaxf(fmaxf(v4, v5), fmaxf(v6, v7)));
            mx = fmaxf(mx, __shfl_xor(mx, 1, 64));   // partner lane: other 8 classes
            float s = __expf(v0 - mx) + __expf(v1 - mx) + __expf(v2 - mx) + __expf(v3 - mx)
                    + __expf(v4 - mx) + __expf(v5 - mx) + __expf(v6 - mx) + __expf(v7 - mx);
            s += __shfl_xor(s, 1, 64);
            float lse = mx + __logf(s);
            if (active) {
                float* o = out + (size_t)c * NCLS + hl * 8;
                *(float4*)&o[0] = make_float4(v0 - lse, v1 - lse, v2 - lse, v3 - lse);
                *(float4*)&o[4] = make_float4(v4 - lse, v5 - lse, v6 - lse, v7 - lse);
            }
        }
    }
}

// ---------------- launch ----------------

extern "C" void kernel_launch(void* const* d_in, const int* in_sizes, int n_in,
                              void* d_out, int out_size, void* d_ws, size_t ws_size,
                              hipStream_t stream) {
    const float* x  = (const float*)d_in[0];
    const int*   ei = (const int*)d_in[1];
    const float* W1 = (const float*)d_in[2];
    const float* b1 = (const float*)d_in[3];
    const float* W2 = (const float*)d_in[4];
    const float* b2 = (const float*)d_in[5];
    float* out = (float*)d_out;

    const int N = in_sizes[0] / F_IN;
    const int E = in_sizes[1] / 2;
    const int* row = ei;        // edge_index[0] = source
    const int* col = ei + E;    // edge_index[1] = destination

    const int NB = (N + NPB - 1) / NPB;          // buckets; must be <= 1024
    size_t Np  = ((size_t)N + 15) & ~(size_t)15;
    size_t NBp = ((size_t)NB + 15) & ~(size_t)15;
    size_t Rg  = (size_t)NB * CAP;               // capped region space (edge slots)

    char* p = (char*)d_ws;
    __half* hs1     = (__half*)p;  p += Np * HID * 2;
    __half* h2s     = (__half*)p;  p += Np * NCLS * 2;
    half_t* W1t     = (half_t*)p;  p += (size_t)F_IN * HID * 2;
    int2*   rsc     = (int2*)p;    p += Np * 8;       // per-node (start, count)
    int*    csr_row = (int*)p;     p += Rg * 4;
    int*    ebuf    = (int*)p;     p += Rg * 4;
    int*    cursor  = (int*)p;     p += NBp * 4;
    int*    bar     = (int*)p;     p += 64;           // [0]=cnt, [1]=gen (own line)

    // Occupancy-clamped persistent grid (co-residency by construction).
    static int s_grid = 0;
    if (!s_grid) {
        int dev = 0;
        hipGetDevice(&dev);
        hipDeviceProp_t prop;
        int ncu = 256;
        if (hipGetDeviceProperties(&prop, dev) == hipSuccess) ncu = prop.multiProcessorCount;
        int perCU = 0;
        if (hipOccupancyMaxActiveBlocksPerMultiprocessor(&perCU, fused_gcn, 256, 0) != hipSuccess || perCU < 1)
            perCU = 2;
        long cap = (long)ncu * perCU;
        s_grid = (int)(cap < 1024 ? cap : 1024);
        if (s_grid < 1) s_grid = 1;
    }

    hipMemsetAsync(cursor, 0, NBp * sizeof(int) + 64, stream);
    fused_gcn<<<s_grid, 256, 0, stream>>>(row, col, x, W1, b1, W2, b2, out,
                                          cursor, ebuf, W1t, rsc, csr_row,
                                          hs1, h2s, bar, N, E, NB);
}

// Round 4
// 286.067 us; speedup vs baseline: 2.0912x; 2.0912x over previous
//
#include <hip/hip_runtime.h>
#include <hip/hip_fp16.h>

#define F_IN 128
#define HID  64
#define NCLS 16
#define NPB  128      // nodes per bucket (pow2); bucket = node >> 7
#define CAP  4096     // csr_row slots reserved per bucket (2x mean 2046)
#define CHUNK 4096    // edges per edge-parallel block (= 4 * 1024)

typedef _Float16 half_t;
typedef __attribute__((ext_vector_type(8))) _Float16 half8;
typedef __attribute__((ext_vector_type(4))) float float4v;

// ---------------- k1: per-node in-degree (global atomics) + W1 transpose ----------------

__global__ __launch_bounds__(256) void deg_w1(
    const int* __restrict__ col, const float* __restrict__ W1,
    int* __restrict__ deg, half_t* __restrict__ W1t, int E, int nch)
{
    if ((int)blockIdx.x >= nch) {                 // W1 prep block
        for (int i = threadIdx.x; i < F_IN * HID; i += 256) {
            int k = i >> 6, n = i & 63;
            W1t[n * F_IN + k] = (half_t)W1[i];
        }
        return;
    }
    int base = blockIdx.x * CHUNK;
    #pragma unroll
    for (int j = 0; j < 4; ++j) {                 // 4 coalesced sweeps of 4 KB
        int ej = base + j * (CHUNK / 4) + threadIdx.x * 4;
        if (ej + 4 <= E) {
            int4 c4 = *(const int4*)&col[ej];
            atomicAdd(&deg[c4.x], 1);
            atomicAdd(&deg[c4.y], 1);
            atomicAdd(&deg[c4.z], 1);
            atomicAdd(&deg[c4.w], 1);
        } else {
            for (int q = ej; q < E; ++q) atomicAdd(&deg[col[q]], 1);
        }
    }
}

// ---------------- k2: per-bucket exclusive scan of deg -> rsc + scatter cursors ----------------

__global__ __launch_bounds__(128) void scan_init(
    const int* __restrict__ deg, int2* __restrict__ rsc,
    int* __restrict__ curg, int N)
{
    __shared__ int wtot;
    int b = blockIdx.x, t = threadIdx.x;
    int n = (b << 7) + t;
    int h = (n < N) ? deg[n] : 0;
    int incl = h;
    #pragma unroll
    for (int off = 1; off < 64; off <<= 1) {
        int u = __shfl_up(incl, off, 64);
        if ((t & 63) >= off) incl += u;
    }
    if (t == 63) wtot = incl;
    __syncthreads();
    if (t >= 64) incl += wtot;
    int start = b * CAP + incl - h;               // exclusive, bucket-region space
    if (n < N) {
        rsc[n] = make_int2(start, h);
        curg[n] = start;
    }
}

// ---------------- k3: ONE dispatch, two independent families ----------------
// Blocks [0, nch):        edge scatter: csr_row[atomicAdd(curg[col])] = row
// Blocks [nch, nch+NB):   128x64 MFMA GEMM for bucket b (dv from deg directly)

__global__ __launch_bounds__(256) void scatter_gemm(
    const int* __restrict__ row, const int* __restrict__ col,
    int* __restrict__ curg, int* __restrict__ csr_row,
    const float* __restrict__ x, const half_t* __restrict__ W1t,
    const int* __restrict__ deg, __half* __restrict__ hs1,
    int N, int E, int nch)
{
    int t = threadIdx.x;
    if ((int)blockIdx.x < nch) {
        // ---- scatter family ----
        int base = blockIdx.x * CHUNK;
        #pragma unroll
        for (int j = 0; j < 4; ++j) {
            int ej = base + j * (CHUNK / 4) + t * 4;
            if (ej + 4 <= E) {
                int4 c4 = *(const int4*)&col[ej];
                int4 r4 = *(const int4*)&row[ej];
                int p0 = atomicAdd(&curg[c4.x], 1);
                if (p0 < ((c4.x >> 7) + 1) * CAP) csr_row[p0] = r4.x;
                int p1 = atomicAdd(&curg[c4.y], 1);
                if (p1 < ((c4.y >> 7) + 1) * CAP) csr_row[p1] = r4.y;
                int p2 = atomicAdd(&curg[c4.z], 1);
                if (p2 < ((c4.z >> 7) + 1) * CAP) csr_row[p2] = r4.z;
                int p3 = atomicAdd(&curg[c4.w], 1);
                if (p3 < ((c4.w >> 7) + 1) * CAP) csr_row[p3] = r4.w;
            } else {
                for (int q = ej; q < E; ++q) {
                    int c = col[q];
                    int p = atomicAdd(&curg[c], 1);
                    if (p < ((c >> 7) + 1) * CAP) csr_row[p] = row[q];
                }
            }
        }
        return;
    }

    // ---- GEMM family ----
    __shared__ float dv[NPB];
    int b = blockIdx.x - nch;
    int node0 = b << 7;
    if (t < NPB) {
        int n = node0 + t;
        dv[t] = rsqrtf((float)((n < N) ? deg[n] : 0) + 1.0f);   // +1 = self-loop
    }
    __syncthreads();

    // 128x64 MFMA GEMM, K=128: wave wv = m rows [32wv, 32wv+32)
    int wv = t >> 6, lane = t & 63;
    int l15 = lane & 15, quad = lane >> 4;
    int mbase = wv * 32;
    int r0 = min(node0 + mbase + l15, N - 1);
    int r1 = min(node0 + mbase + 16 + l15, N - 1);
    const float* x0 = x + (size_t)r0 * F_IN;
    const float* x1 = x + (size_t)r1 * F_IN;
    float4v acc[2][4];
    #pragma unroll
    for (int mt = 0; mt < 2; ++mt)
        #pragma unroll
        for (int j = 0; j < 4; ++j) acc[mt][j] = (float4v){0.f, 0.f, 0.f, 0.f};
    #pragma unroll
    for (int kb = 0; kb < 4; ++kb) {
        int off = kb * 32 + quad * 8;
        float4 fa = *(const float4*)&x0[off];
        float4 fb = *(const float4*)&x0[off + 4];
        float4 ga = *(const float4*)&x1[off];
        float4 gb = *(const float4*)&x1[off + 4];
        half8 a0 = {(half_t)fa.x, (half_t)fa.y, (half_t)fa.z, (half_t)fa.w,
                    (half_t)fb.x, (half_t)fb.y, (half_t)fb.z, (half_t)fb.w};
        half8 a1 = {(half_t)ga.x, (half_t)ga.y, (half_t)ga.z, (half_t)ga.w,
                    (half_t)gb.x, (half_t)gb.y, (half_t)gb.z, (half_t)gb.w};
        #pragma unroll
        for (int j = 0; j < 4; ++j) {
            half8 bv = *(const half8*)&W1t[(size_t)(j * 16 + l15) * F_IN + off];
            acc[0][j] = __builtin_amdgcn_mfma_f32_16x16x32_f16(a0, bv, acc[0][j], 0, 0, 0);
            acc[1][j] = __builtin_amdgcn_mfma_f32_16x16x32_f16(a1, bv, acc[1][j], 0, 0, 0);
        }
    }
    // C/D: col(n) = l15, row(m) = quad*4 + r
    #pragma unroll
    for (int mt = 0; mt < 2; ++mt)
        #pragma unroll
        for (int j = 0; j < 4; ++j)
            #pragma unroll
            for (int r = 0; r < 4; ++r) {
                int m = mbase + mt * 16 + quad * 4 + r;
                int n = node0 + m;
                if (n < N) hs1[(size_t)n * HID + j * 16 + l15] =
                    __float2half(acc[mt][j][r] * dv[m]);
            }
}

// ---------------- layer-1 gather-aggregate + relu + @W2 ----------------
// 8 lanes per node (8 nodes/wave, 32/block). Lane owns 8 feats: one half8
// (16B) gather per edge. Main loop: full 8-edge blocks, no predication,
// packed-fp16 pairwise reduction tree then f32 accumulate.

__global__ __launch_bounds__(256) void agg_l1(
    const __half* __restrict__ hs1, const int2* __restrict__ rsc,
    const int* __restrict__ csr, const float* __restrict__ b1,
    const float* __restrict__ W2, __half* __restrict__ h2s, int N)
{
    __shared__ float W2l[HID * NCLS];     // 4 KB, index k*16+j
    __shared__ float o1[32][65];          // stride 65: wave's rows on distinct banks
    for (int i = threadIdx.x; i < HID * NCLS; i += 256) W2l[i] = W2[i];
    __syncthreads();
    int w = threadIdx.x >> 6, lane = threadIdx.x & 63;
    int g = lane >> 3, gl = lane & 7;
    int rowi = w * 8 + g;
    int c = blockIdx.x * 32 + rowi;
    bool active = (c < N);
    int cc = active ? c : 0;
    int2 rc = rsc[cc];
    int e0 = rc.x, e1 = rc.x + rc.y;
    float dc = rsqrtf((float)rc.y + 1.0f);
    const half8* H = (const half8*)hs1;   // 8 half8 per row
    half8 sv = H[(size_t)cc * 8 + gl];    // self-loop (hs1 pre-scaled by dinv[src])
    float sum[8];
    #pragma unroll
    for (int k = 0; k < 8; ++k) sum[k] = (float)sv[k];
    int i = e0;
    for (; i + 8 <= e1; i += 8) {         // full blocks: no min, no predication
        int id[8];
        #pragma unroll
        for (int s = 0; s < 8; ++s) id[s] = csr[i + s];
        half8 a[8];
        #pragma unroll
        for (int s = 0; s < 8; ++s) a[s] = H[(size_t)id[s] * 8 + gl];
        half8 t0 = a[0] + a[1];           // packed-fp16 pairwise tree
        half8 t1 = a[2] + a[3];
        half8 t2 = a[4] + a[5];
        half8 t3 = a[6] + a[7];
        half8 v = (t0 + t1) + (t2 + t3);
        #pragma unroll
        for (int k = 0; k < 8; ++k) sum[k] += (float)v[k];
    }
    if (i < e1) {                          // tail (<8 edges), predicated
        int e1m1 = e1 - 1;
        int id[8];
        #pragma unroll
        for (int s = 0; s < 8; ++s) id[s] = csr[min(i + s, e1m1)];
        half8 a[8];
        #pragma unroll
        for (int s = 0; s < 8; ++s) a[s] = H[(size_t)id[s] * 8 + gl];
        #pragma unroll
        for (int s = 0; s < 8; ++s) {
            float fm = (i + s < e1) ? 1.f : 0.f;
            #pragma unroll
            for (int k = 0; k < 8; ++k) sum[k] = fmaf(fm, (float)a[s][k], sum[k]);
        }
    }
    float4 bb0 = *(const float4*)&b1[gl * 8];
    float4 bb1 = *(const float4*)&b1[gl * 8 + 4];
    o1[rowi][gl * 8 + 0] = fmaxf(fmaf(dc, sum[0], bb0.x), 0.f);
    o1[rowi][gl * 8 + 1] = fmaxf(fmaf(dc, sum[1], bb0.y), 0.f);
    o1[rowi][gl * 8 + 2] = fmaxf(fmaf(dc, sum[2], bb0.z), 0.f);
    o1[rowi][gl * 8 + 3] = fmaxf(fmaf(dc, sum[3], bb0.w), 0.f);
    o1[rowi][gl * 8 + 4] = fmaxf(fmaf(dc, sum[4], bb1.x), 0.f);
    o1[rowi][gl * 8 + 5] = fmaxf(fmaf(dc, sum[5], bb1.y), 0.f);
    o1[rowi][gl * 8 + 6] = fmaxf(fmaf(dc, sum[6], bb1.z), 0.f);
    o1[rowi][gl * 8 + 7] = fmaxf(fmaf(dc, sum[7], bb1.w), 0.f);
    // same-wave LDS write->read: no barrier needed.
    int j0 = gl * 2, j1 = gl * 2 + 1;
    float s0 = 0.f, s1 = 0.f;
    const float* orow = o1[rowi];
    #pragma unroll 8
    for (int k = 0; k < HID; ++k) {
        float ov = orow[k];
        s0 = fmaf(ov, W2l[k * NCLS + j0], s0);
        s1 = fmaf(ov, W2l[k * NCLS + j1], s1);
    }
    if (active) {
        __half2 hv;
        hv.x = __float2half(dc * s0);
        hv.y = __float2half(dc * s1);
        ((__half2*)h2s)[(size_t)c * 8 + gl] = hv;
    }
}

// ---------------- layer-2 gather-aggregate + log_softmax ----------------
// 2 lanes per node (32 nodes/wave, 128/block). Lane owns 8 of the 16 classes:
// one half8 (16B) gather per edge. Packed-fp16 tree, f32 accumulate,
// pairwise-lane log_softmax via shfl_xor(1).

__global__ __launch_bounds__(256) void agg2_final(
    const __half* __restrict__ h2s, const int2* __restrict__ rsc,
    const int* __restrict__ csr, const float* __restrict__ b2,
    float* __restrict__ out, int N)
{
    int t = threadIdx.x;
    int w = t >> 6, lane = t & 63;
    int nw = lane >> 1, hl = lane & 1;
    int c = blockIdx.x * 128 + w * 32 + nw;
    bool active = (c < N);
    int cc = active ? c : 0;
    int2 rc = rsc[cc];
    int e0 = rc.x, e1 = rc.x + rc.y;
    float dcv = rsqrtf((float)rc.y + 1.0f);
    const half8* H = (const half8*)h2s;       // 2 half8 per row (32B)
    half8 sv = H[(size_t)cc * 2 + hl];        // self-loop
    float sum[8];
    #pragma unroll
    for (int k = 0; k < 8; ++k) sum[k] = (float)sv[k];
    int i = e0;
    for (; i + 8 <= e1; i += 8) {             // full blocks: packed-fp16 tree
        int id[8];
        #pragma unroll
        for (int s = 0; s < 8; ++s) id[s] = csr[i + s];
        half8 a[8];
        #pragma unroll
        for (int s = 0; s < 8; ++s) a[s] = H[(size_t)id[s] * 2 + hl];
        half8 t0 = a[0] + a[1];
        half8 t1 = a[2] + a[3];
        half8 t2 = a[4] + a[5];
        half8 t3 = a[6] + a[7];
        half8 v = (t0 + t1) + (t2 + t3);
        #pragma unroll
        for (int k = 0; k < 8; ++k) sum[k] += (float)v[k];
    }
    if (i < e1) {                              // tail (<8 edges), predicated
        int e1m1 = e1 - 1;
        int id[8];
        #pragma unroll
        for (int s = 0; s < 8; ++s) id[s] = csr[min(i + s, e1m1)];
        half8 a[8];
        #pragma unroll
        for (int s = 0; s < 8; ++s) a[s] = H[(size_t)id[s] * 2 + hl];
        #pragma unroll
        for (int s = 0; s < 8; ++s) {
            float fm = (i + s < e1) ? 1.f : 0.f;
            #pragma unroll
            for (int k = 0; k < 8; ++k) sum[k] = fmaf(fm, (float)a[s][k], sum[k]);
        }
    }
    float4 bb0 = *(const float4*)&b2[hl * 8];
    float4 bb1 = *(const float4*)&b2[hl * 8 + 4];
    float v0 = fmaf(dcv, sum[0], bb0.x);
    float v1 = fmaf(dcv, sum[1], bb0.y);
    float v2 = fmaf(dcv, sum[2], bb0.z);
    float v3 = fmaf(dcv, sum[3], bb0.w);
    float v4 = fmaf(dcv, sum[4], bb1.x);
    float v5 = fmaf(dcv, sum[5], bb1.y);
    float v6 = fmaf(dcv, sum[6], bb1.z);
    float v7 = fmaf(dcv, sum[7], bb1.w);
    float mx = fmaxf(fmaxf(fmaxf(v0, v1), fmaxf(v2, v3)),
                     fmaxf(fmaxf(v4, v5), fmaxf(v6, v7)));
    mx = fmaxf(mx, __shfl_xor(mx, 1, 64));     // partner lane holds other 8 classes
    float s = __expf(v0 - mx) + __expf(v1 - mx) + __expf(v2 - mx) + __expf(v3 - mx)
            + __expf(v4 - mx) + __expf(v5 - mx) + __expf(v6 - mx) + __expf(v7 - mx);
    s += __shfl_xor(s, 1, 64);
    float lse = mx + __logf(s);
    if (active) {
        float* o = out + (size_t)c * NCLS + hl * 8;
        *(float4*)&o[0] = make_float4(v0 - lse, v1 - lse, v2 - lse, v3 - lse);
        *(float4*)&o[4] = make_float4(v4 - lse, v5 - lse, v6 - lse, v7 - lse);
    }
}

// ---------------- launch ----------------

extern "C" void kernel_launch(void* const* d_in, const int* in_sizes, int n_in,
                              void* d_out, int out_size, void* d_ws, size_t ws_size,
                              hipStream_t stream) {
    const float* x  = (const float*)d_in[0];
    const int*   ei = (const int*)d_in[1];
    const float* W1 = (const float*)d_in[2];
    const float* b1 = (const float*)d_in[3];
    const float* W2 = (const float*)d_in[4];
    const float* b2 = (const float*)d_in[5];
    float* out = (float*)d_out;

    const int N = in_sizes[0] / F_IN;
    const int E = in_sizes[1] / 2;
    const int* row = ei;        // edge_index[0] = source
    const int* col = ei + E;    // edge_index[1] = destination

    const int NB = (N + NPB - 1) / NPB;          // buckets
    size_t Np  = ((size_t)N + 15) & ~(size_t)15;
    size_t Rg  = (size_t)NB * CAP;               // capped region space (edge slots)

    char* p = (char*)d_ws;
    __half* hs1     = (__half*)p;  p += Np * HID * 2;
    __half* h2s     = (__half*)p;  p += Np * NCLS * 2;
    half_t* W1t     = (half_t*)p;  p += (size_t)F_IN * HID * 2;
    int2*   rsc     = (int2*)p;    p += Np * 8;       // per-node (start, count)
    int*    csr_row = (int*)p;     p += Rg * 4;
    int*    deg     = (int*)p;     p += Np * 4;
    int*    curg    = (int*)p;     p += Np * 4;

    int nch = (E + CHUNK - 1) / CHUNK;

    hipMemsetAsync(deg, 0, Np * sizeof(int), stream);
    deg_w1<<<nch + 1, 256, 0, stream>>>(col, W1, deg, W1t, E, nch);
    scan_init<<<NB, 128, 0, stream>>>(deg, rsc, curg, N);
    scatter_gemm<<<nch + NB, 256, 0, stream>>>(row, col, curg, csr_row, x, W1t,
                                               deg, hs1, N, E, nch);
    agg_l1<<<(N + 31) / 32, 256, 0, stream>>>(hs1, rsc, csr_row, b1, W2, h2s, N);
    agg2_final<<<(N + 127) / 128, 256, 0, stream>>>(h2s, rsc, csr_row, b2, out, N);
}